// Round 3
// baseline (208.763 us; speedup 1.0000x reference)
//
#include <hip/hip_runtime.h>
#include <hip/hip_bf16.h>

typedef __attribute__((ext_vector_type(8))) _Float16 f16x8;  // 8 fp16 (4 VGPR)
typedef __attribute__((ext_vector_type(4))) float f32x4;     // MFMA C/D frag

constexpr int Sc  = 2048;
constexpr int Dc  = 1024;
constexpr int Hc  = 16;
constexpr int HDc = 64;
constexpr int Mc  = 4096;  // B*S

constexpr float ECs = 0.18033688011112042f;  // log2(e)/8, folded into Q

// ---------------------------------------------------------------------------
// fp16 helper (RNE via v_cvt_f16_f32)
// ---------------------------------------------------------------------------
__device__ __forceinline__ ushort f2h(float f) {
  return __builtin_bit_cast(ushort, (_Float16)f);
}

union US8 {
  ushort u[8];
  uint   w[4];
  f16x8  v;
};

// ---------------------------------------------------------------------------
// split_x: x fp32 [M,1024] -> fp16 (row-major). 1 float4/thread.
// ---------------------------------------------------------------------------
__global__ __launch_bounds__(256) void split_x_kernel(
    const float* __restrict__ X, ushort* __restrict__ H) {
  const int i    = blockIdx.x * 256 + threadIdx.x;
  const float4 v = ((const float4*)X)[i];
  ushort4 h;
  h.x = f2h(v.x);
  h.y = f2h(v.y);
  h.z = f2h(v.z);
  h.w = f2h(v.w);
  ((ushort4*)H)[i] = h;
}

// ---------------------------------------------------------------------------
// split_wt: W[k][n] fp32 -> T fp16 [n][k] (transpose).
// ---------------------------------------------------------------------------
struct SplitP {
  const float* W[4];
  ushort*      Th[4];
};

__global__ __launch_bounds__(256) void split_wt_kernel(SplitP p) {
  __shared__ float T[64][69];
  const int z = blockIdx.z;
  const float* W = p.W[z];
  const int t  = threadIdx.x;
  const int c  = (t & 15) * 4;
  const int r  = t >> 4;
  const int n0 = blockIdx.x * 64, k0 = blockIdx.y * 64;
#pragma unroll
  for (int pp = 0; pp < 4; ++pp) {
    const int k    = r + pp * 16;
    const float4 v = *(const float4*)(W + (size_t)(k0 + k) * 1024 + n0 + c);
    T[k][c + 0] = v.x;
    T[k][c + 1] = v.y;
    T[k][c + 2] = v.z;
    T[k][c + 3] = v.w;
  }
  __syncthreads();
#pragma unroll
  for (int pp = 0; pp < 4; ++pp) {
    const int n = r + pp * 16;
    ushort4 h;
    h.x = f2h(T[c + 0][n]);
    h.y = f2h(T[c + 1][n]);
    h.z = f2h(T[c + 2][n]);
    h.w = f2h(T[c + 3][n]);
    *(ushort4*)(p.Th[z] + (size_t)(n0 + n) * 1024 + k0 + c) = h;
  }
}

// ---------------------------------------------------------------------------
// fp16 MFMA GEMM with register-prefetch pipeline + XOR-swizzled LDS.
//  QKV=true : out fp16 [B,H,S,HD]; z 0..2; z==0 (Q) epilogue pre-scales by
//             log2(e)/8 for the attn exp2.
//  QKV=false: out fp32 [M,1024] (final).
// ---------------------------------------------------------------------------
struct GemmP {
  const ushort* Bh[3];
  const float*  bias[3];
  void*         Out[3];
};

template <bool QKV>
__global__ __launch_bounds__(256) void gemm_f16(
    const ushort* __restrict__ A, GemmP p) {
  __shared__ __align__(16) ushort As[128 * 32];
  __shared__ __align__(16) ushort Bs[128 * 32];

  const int t  = threadIdx.x;
  const int z  = blockIdx.z;
  const int m0 = blockIdx.x * 128, n0 = blockIdx.y * 128;
  const ushort* Bh  = p.Bh[z];
  const float* bias = p.bias[z];

  const int lane = t & 63, wave = t >> 6;
  const int wm = (wave & 1) * 64, wn = (wave >> 1) * 64;

  f32x4 acc[4][4];
#pragma unroll
  for (int i = 0; i < 4; ++i)
#pragma unroll
    for (int j = 0; j < 4; ++j) acc[i][j] = (f32x4){0.f, 0.f, 0.f, 0.f};

  // staging: rows {am, am+64}, logical chunk ac (8 elems)
  const int am = t >> 2;
  const int ac = t & 3;
  const ushort* gA  = A  + (size_t)(m0 + am) * 1024 + ac * 8;
  const ushort* gBh = Bh + (size_t)(n0 + am) * 1024 + ac * 8;
  const int sw = ((ac + (am >> 1)) & 3) * 8;  // physical elem offset (both rows)
  const int l0 = am * 32 + sw, l1 = (am + 64) * 32 + sw;

  const int fr  = lane & 15;
  const int fkb = (((lane >> 4) + (fr >> 1)) & 3) * 16;  // byte offset

  // preload tile k0=0
  f16x8 rA0, rA1, rH0, rH1;
  rA0 = *(const f16x8*)(gA);
  rA1 = *(const f16x8*)(gA + 64 * 1024);
  rH0 = *(const f16x8*)(gBh);
  rH1 = *(const f16x8*)(gBh + 64 * 1024);

  for (int k0 = 0; k0 < 1024; k0 += 32) {
    __syncthreads();  // prev compute done reading LDS
    *(f16x8*)&As[l0] = rA0;
    *(f16x8*)&As[l1] = rA1;
    *(f16x8*)&Bs[l0] = rH0;
    *(f16x8*)&Bs[l1] = rH1;
    __syncthreads();

    // prefetch next tile (overlaps the whole compute phase)
    if (k0 + 32 < 1024) {
      const int kn = k0 + 32;
      rA0 = *(const f16x8*)(gA + kn);
      rA1 = *(const f16x8*)(gA + kn + 64 * 1024);
      rH0 = *(const f16x8*)(gBh + kn);
      rH1 = *(const f16x8*)(gBh + kn + 64 * 1024);
    }

    f16x8 a[4], b_h[4];
#pragma unroll
    for (int i = 0; i < 4; ++i) {
      const int ra = (wm + i * 16 + fr) * 64 + fkb;  // bytes
      const int rb = (wn + i * 16 + fr) * 64 + fkb;
      a[i]   = *(const f16x8*)((const char*)As + ra);
      b_h[i] = *(const f16x8*)((const char*)Bs + rb);
    }
#pragma unroll
    for (int i = 0; i < 4; ++i)
#pragma unroll
      for (int j = 0; j < 4; ++j)
        acc[i][j] = __builtin_amdgcn_mfma_f32_16x16x32_f16(a[i], b_h[j], acc[i][j], 0, 0, 0);
  }

  const float osc = (QKV && z == 0) ? ECs : 1.0f;  // fold softmax scale into Q
  const int cr = (lane >> 4) * 4;
  const int cc = lane & 15;
#pragma unroll
  for (int j = 0; j < 4; ++j) {
    const int n    = n0 + wn + j * 16 + cc;
    const float bv = bias[n];
#pragma unroll
    for (int i = 0; i < 4; ++i) {
      const int mb = m0 + wm + i * 16 + cr;
#pragma unroll
      for (int r = 0; r < 4; ++r) {
        const int m   = mb + r;
        const float v = (acc[i][j][r] + bv) * osc;
        if (QKV) {
          const int b = m >> 11, s = m & 2047, h = n >> 6, hd = n & 63;
          ((ushort*)p.Out[z])[(((size_t)(b * Hc + h) * Sc + s) << 6) + hd] = f2h(v);
        } else {
          ((float*)p.Out[z])[(size_t)m * 1024 + n] = v;
        }
      }
    }
  }
}

// ---------------------------------------------------------------------------
// MFMA flash attention, split-KV x2.
// blockIdx.z selects half the KV range (16 of 32 tiles) -> 1024 blocks
// (4/CU, 16 waves/CU) instead of 512 (2/CU): fills the latency gaps that
// capped the single-pass version at Occupancy 18% / MfmaUtil 27%.
// Output: UNNORMALIZED ctx partial (fp16, plane z) + per-row P-sum (f32);
// a separate combine kernel normalizes. QK^T zero-init hoisted: first MFMA
// takes a loop-invariant zero C operand (saves 32 v_mov/thread/kt).
// ---------------------------------------------------------------------------
__global__ __launch_bounds__(256) void attn_mfma3(
    const ushort* __restrict__ Q, const ushort* __restrict__ K,
    const ushort* __restrict__ V, ushort* __restrict__ CTXP,
    float* __restrict__ LACC) {
  __shared__ __align__(16) ushort Ks[64 * 72];
  __shared__ __align__(16) ushort Vt[64 * 72];  // [d][l(k)]

  const int t    = threadIdx.x;
  const int lane = t & 63, wave = t >> 6;
  const int c16 = lane & 15, quad = lane >> 4;
  const int bh = blockIdx.x, qt = blockIdx.y, z = blockIdx.z;
  const int bb = bh >> 4, hh = bh & 15;

  const ushort* Qb = Q + (size_t)bh * Sc * HDc + (size_t)qt * 128 * HDc;
  const ushort* Kb = K + (size_t)bh * Sc * HDc + (size_t)z * 16 * 64 * HDc;
  const ushort* Vb = V + (size_t)bh * Sc * HDc + (size_t)z * 16 * 64 * HDc;

  f16x8 aq[2][2];
#pragma unroll
  for (int mt = 0; mt < 2; ++mt)
#pragma unroll
    for (int c = 0; c < 2; ++c)
      aq[mt][c] = *(const f16x8*)(Qb + (size_t)(wave * 32 + mt * 16 + c16) * 64 + c * 32 + quad * 8);

  US8 ones_u;
#pragma unroll
  for (int e = 0; e < 8; ++e) ones_u.u[e] = 0x3C00;  // fp16 1.0
  const f16x8 ones = ones_u.v;
  const f32x4 kZ = (f32x4){0.f, 0.f, 0.f, 0.f};  // hoisted MFMA C=0

  f32x4 ctx[2][4], lacc[2];
#pragma unroll
  for (int mt = 0; mt < 2; ++mt) {
    lacc[mt] = (f32x4){0.f, 0.f, 0.f, 0.f};
#pragma unroll
    for (int j = 0; j < 4; ++j) ctx[mt][j] = (f32x4){0.f, 0.f, 0.f, 0.f};
  }

  const int krow = t >> 2, kc = (t & 3) * 8;
  const int kg = t & 15, dg = t >> 4;
  const int lb = ((kg >> 3) << 5) | ((kg & 3) << 3) | (((kg >> 2) & 1) << 2);

  const ushort* gK = Kb + (size_t)krow * 64 + kc;
  const ushort* gV = Vb + (size_t)(kg * 4) * 64 + dg * 4;

  f16x8 kr0, kr1;
  ushort4 vr[4];
  kr0 = *(const f16x8*)(gK);
  kr1 = *(const f16x8*)(gK + 32);
#pragma unroll
  for (int i = 0; i < 4; ++i) vr[i] = *(const ushort4*)(gV + (size_t)i * 64);

  for (int kt = 0; kt < 16; ++kt) {
    __syncthreads();
    *(f16x8*)&Ks[krow * 72 + kc]      = kr0;
    *(f16x8*)&Ks[krow * 72 + kc + 32] = kr1;
    {
      const uint* w0 = (const uint*)&vr[0];
      const uint* w1 = (const uint*)&vr[1];
      const uint* w2 = (const uint*)&vr[2];
      const uint* w3 = (const uint*)&vr[3];
#pragma unroll
      for (int j = 0; j < 4; ++j) {
        const int  wd  = j >> 1;
        const uint sel = (j & 1) ? 0x07060302u : 0x05040100u;
        const uint lo  = __builtin_amdgcn_perm(w1[wd], w0[wd], sel);
        const uint hi  = __builtin_amdgcn_perm(w3[wd], w2[wd], sel);
        *(uint2*)&Vt[(dg * 4 + j) * 72 + lb] = make_uint2(lo, hi);
      }
    }
    __syncthreads();

    if (kt < 15) {
      const size_t adv = (size_t)(kt + 1) * 64 * 64;
      kr0 = *(const f16x8*)(gK + adv);
      kr1 = *(const f16x8*)(gK + adv + 32);
#pragma unroll
      for (int i = 0; i < 4; ++i) vr[i] = *(const ushort4*)(gV + adv + (size_t)i * 64);
    }

    // QK^T: c=0 uses the hoisted zero C operand (no per-kt acc zeroing)
    f32x4 st[2][4];
#pragma unroll
    for (int j = 0; j < 4; ++j) {
      const f16x8 ak0 = *(const f16x8*)&Ks[(j * 16 + c16) * 72 + quad * 8];
      st[0][j] = __builtin_amdgcn_mfma_f32_16x16x32_f16(ak0, aq[0][0], kZ, 0, 0, 0);
      st[1][j] = __builtin_amdgcn_mfma_f32_16x16x32_f16(ak0, aq[1][0], kZ, 0, 0, 0);
    }
#pragma unroll
    for (int j = 0; j < 4; ++j) {
      const f16x8 ak1 = *(const f16x8*)&Ks[(j * 16 + c16) * 72 + 32 + quad * 8];
      st[0][j] = __builtin_amdgcn_mfma_f32_16x16x32_f16(ak1, aq[0][1], st[0][j], 0, 0, 0);
      st[1][j] = __builtin_amdgcn_mfma_f32_16x16x32_f16(ak1, aq[1][1], st[1][j], 0, 0, 0);
    }

    US8 pf[2][2];
#pragma unroll
    for (int mt = 0; mt < 2; ++mt)
#pragma unroll
      for (int c2 = 0; c2 < 2; ++c2)
#pragma unroll
        for (int w = 0; w < 4; ++w) {
          const int jj = c2 * 2 + (w >> 1);
          const int r0 = (w & 1) * 2;
          const float pe = __builtin_amdgcn_exp2f(st[mt][jj][r0]);
          const float po = __builtin_amdgcn_exp2f(st[mt][jj][r0 + 1]);
          const auto pk = __builtin_amdgcn_cvt_pkrtz(pe, po);  // __fp16 ext_vec(2)
          pf[mt][c2].w[w] = __builtin_bit_cast(uint, pk);
        }

#pragma unroll
    for (int c2 = 0; c2 < 2; ++c2) {
      lacc[0] = __builtin_amdgcn_mfma_f32_16x16x32_f16(pf[0][c2].v, ones, lacc[0], 0, 0, 0);
      lacc[1] = __builtin_amdgcn_mfma_f32_16x16x32_f16(pf[1][c2].v, ones, lacc[1], 0, 0, 0);
#pragma unroll
      for (int j = 0; j < 4; ++j) {
        const f16x8 bv = *(const f16x8*)&Vt[(j * 16 + c16) * 72 + c2 * 32 + quad * 8];
        ctx[0][j] = __builtin_amdgcn_mfma_f32_16x16x32_f16(pf[0][c2].v, bv, ctx[0][j], 0, 0, 0);
        ctx[1][j] = __builtin_amdgcn_mfma_f32_16x16x32_f16(pf[1][c2].v, bv, ctx[1][j], 0, 0, 0);
      }
    }
  }

  // epilogue: unnormalized ctx partial (plane z) + row P-sums
  ushort* Cp = CTXP + (size_t)z * Mc * 1024;
  float*  Lp = LACC + (size_t)z * 2 * Hc * Sc;
#pragma unroll
  for (int mt = 0; mt < 2; ++mt) {
#pragma unroll
    for (int r = 0; r < 4; ++r) {
      const int srow  = qt * 128 + wave * 32 + mt * 16 + quad * 4 + r;
      const size_t rb = ((size_t)(bb * Sc + srow)) * 1024 + hh * 64;
#pragma unroll
      for (int j = 0; j < 4; ++j)
        Cp[rb + j * 16 + c16] = f2h(ctx[mt][j][r]);
      if (c16 == 0) Lp[bh * Sc + srow] = lacc[mt][r];
    }
  }
}

// ---------------------------------------------------------------------------
// combine: Cw[m][k] = (Cp0[m][k] + Cp1[m][k]) / (L0[h][m] + L1[h][m]).
// 8 elems/thread, fully coalesced; ~25 MB traffic (HBM-bound, ~4 us).
// ---------------------------------------------------------------------------
__global__ __launch_bounds__(256) void combine_kernel(
    const ushort* __restrict__ CTXP, const float* __restrict__ LACC,
    ushort* __restrict__ Cw) {
  const int i  = blockIdx.x * 256 + threadIdx.x;
  const int m  = i >> 7;
  const int kc = (i & 127) * 8;
  const int b = m >> 11, s = m & 2047, h = kc >> 6;
  const int li = (b * Hc + h) * Sc + s;
  const float l0 = LACC[li];
  const float l1 = LACC[2 * Hc * Sc + li];
  const float inv = 1.f / (l0 + l1);
  US8 c0, c1, o;
  c0.v = *(const f16x8*)(CTXP + (size_t)m * 1024 + kc);
  c1.v = *(const f16x8*)(CTXP + (size_t)Mc * 1024 + (size_t)m * 1024 + kc);
#pragma unroll
  for (int e = 0; e < 8; ++e)
    o.u[e] = f2h(((float)c0.v[e] + (float)c1.v[e]) * inv);
  *(f16x8*)(Cw + (size_t)m * 1024 + kc) = o.v;
}

extern "C" void kernel_launch(void* const* d_in, const int* in_sizes, int n_in,
                              void* d_out, int out_size, void* d_ws, size_t ws_size,
                              hipStream_t stream) {
  (void)in_sizes; (void)n_in; (void)out_size; (void)ws_size;
  const float* x  = (const float*)d_in[0];
  const float* Wq = (const float*)d_in[1];
  const float* bq = (const float*)d_in[2];
  const float* Wk = (const float*)d_in[3];
  const float* bk = (const float*)d_in[4];
  const float* Wv = (const float*)d_in[5];
  const float* bv = (const float*)d_in[6];
  const float* Wo = (const float*)d_in[7];
  const float* bo = (const float*)d_in[8];

  const size_t MB = 1024 * 1024;
  char* w    = (char*)d_ws;
  ushort* Qw  = (ushort*)(w + 0 * MB);   // [B,H,S,HD] fp16 (pre-scaled by EC)
  ushort* Kw  = (ushort*)(w + 8 * MB);
  ushort* Vw  = (ushort*)(w + 16 * MB);
  ushort* Cp  = (ushort*)(w + 24 * MB);  // attn partial z=0 [M,1024] fp16
  ushort* Xh  = (ushort*)(w + 32 * MB);  // x fp16; overlaid by partial z=1
                                         // (free after QKV GEMM)
  ushort* WT  = (ushort*)(w + 40 * MB);  // 4 x 2 MB fp16 W^T planes
  ushort* Whq = WT + 0 * 1048576;
  ushort* Whk = WT + 1 * 1048576;
  ushort* Whv = WT + 2 * 1048576;
  ushort* Who = WT + 3 * 1048576;
  float*  Lp  = (float*)(w + 40 * MB);   // 512 KB, overlays Whq (free after QKV GEMM)
  ushort* Cw  = (ushort*)(w + 48 * MB);  // combined ctx [M,1024] fp16

  const dim3 blk(256);

  split_x_kernel<<<4096, blk, 0, stream>>>(x, Xh);

  SplitP sp;
  sp.W[0] = Wq; sp.W[1] = Wk; sp.W[2] = Wv; sp.W[3] = Wo;
  sp.Th[0] = Whq; sp.Th[1] = Whk; sp.Th[2] = Whv; sp.Th[3] = Who;
  split_wt_kernel<<<dim3(16, 16, 4), blk, 0, stream>>>(sp);

  GemmP pq;
  pq.Bh[0] = Whq; pq.Bh[1] = Whk; pq.Bh[2] = Whv;
  pq.bias[0] = bq; pq.bias[1] = bk; pq.bias[2] = bv;
  pq.Out[0] = Qw; pq.Out[1] = Kw; pq.Out[2] = Vw;
  gemm_f16<true><<<dim3(Mc / 128, Dc / 128, 3), blk, 0, stream>>>(Xh, pq);

  attn_mfma3<<<dim3(2 * Hc, Sc / 128, 2), blk, 0, stream>>>(Qw, Kw, Vw, Cp, Lp);

  combine_kernel<<<Mc * 1024 / 8 / 256, blk, 0, stream>>>(Cp, Lp, Cw);

  GemmP po;
  po.Bh[0] = po.Bh[1] = po.Bh[2] = Who;
  po.bias[0] = po.bias[1] = po.bias[2] = bo;
  po.Out[0] = po.Out[1] = po.Out[2] = d_out;
  gemm_f16<false><<<dim3(Mc / 128, Dc / 128, 1), blk, 0, stream>>>(Cw, po);
}

// Round 5
// 199.178 us; speedup vs baseline: 1.0481x; 1.0481x over previous
//
#include <hip/hip_runtime.h>
#include <hip/hip_bf16.h>

typedef __attribute__((ext_vector_type(8))) _Float16 f16x8;  // 8 fp16 (4 VGPR)
typedef __attribute__((ext_vector_type(4))) float f32x4;     // MFMA C/D frag

constexpr int Sc  = 2048;
constexpr int Dc  = 1024;
constexpr int Hc  = 16;
constexpr int HDc = 64;
constexpr int Mc  = 4096;  // B*S

constexpr float ECs = 0.18033688011112042f;  // log2(e)/8, folded into Q

// ---------------------------------------------------------------------------
// fp16 helper (RNE via v_cvt_f16_f32)
// ---------------------------------------------------------------------------
__device__ __forceinline__ ushort f2h(float f) {
  return __builtin_bit_cast(ushort, (_Float16)f);
}

union US8 {
  ushort u[8];
  uint   w[4];
  f16x8  v;
};

// ---------------------------------------------------------------------------
// split_x: x fp32 [M,1024] -> fp16 (row-major). 1 float4/thread.
// ---------------------------------------------------------------------------
__global__ __launch_bounds__(256) void split_x_kernel(
    const float* __restrict__ X, ushort* __restrict__ H) {
  const int i    = blockIdx.x * 256 + threadIdx.x;
  const float4 v = ((const float4*)X)[i];
  ushort4 h;
  h.x = f2h(v.x);
  h.y = f2h(v.y);
  h.z = f2h(v.z);
  h.w = f2h(v.w);
  ((ushort4*)H)[i] = h;
}

// ---------------------------------------------------------------------------
// split_wt: W[k][n] fp32 -> T fp16 [n][k] (transpose).
// ---------------------------------------------------------------------------
struct SplitP {
  const float* W[4];
  ushort*      Th[4];
};

__global__ __launch_bounds__(256) void split_wt_kernel(SplitP p) {
  __shared__ float T[64][69];
  const int z = blockIdx.z;
  const float* W = p.W[z];
  const int t  = threadIdx.x;
  const int c  = (t & 15) * 4;
  const int r  = t >> 4;
  const int n0 = blockIdx.x * 64, k0 = blockIdx.y * 64;
#pragma unroll
  for (int pp = 0; pp < 4; ++pp) {
    const int k    = r + pp * 16;
    const float4 v = *(const float4*)(W + (size_t)(k0 + k) * 1024 + n0 + c);
    T[k][c + 0] = v.x;
    T[k][c + 1] = v.y;
    T[k][c + 2] = v.z;
    T[k][c + 3] = v.w;
  }
  __syncthreads();
#pragma unroll
  for (int pp = 0; pp < 4; ++pp) {
    const int n = r + pp * 16;
    ushort4 h;
    h.x = f2h(T[c + 0][n]);
    h.y = f2h(T[c + 1][n]);
    h.z = f2h(T[c + 2][n]);
    h.w = f2h(T[c + 3][n]);
    *(ushort4*)(p.Th[z] + (size_t)(n0 + n) * 1024 + k0 + c) = h;
  }
}

// ---------------------------------------------------------------------------
// fp16 MFMA GEMM with register-prefetch pipeline + XOR-swizzled LDS.
//  QKV=true : out fp16 [B,H,S,HD]; z 0..2; z==0 (Q) epilogue pre-scales by
//             log2(e)/8 for the attn exp2.
//  QKV=false: out fp32 [M,1024] (final).
// ---------------------------------------------------------------------------
struct GemmP {
  const ushort* Bh[3];
  const float*  bias[3];
  void*         Out[3];
};

template <bool QKV>
__global__ __launch_bounds__(256) void gemm_f16(
    const ushort* __restrict__ A, GemmP p) {
  __shared__ __align__(16) ushort As[128 * 32];
  __shared__ __align__(16) ushort Bs[128 * 32];

  const int t  = threadIdx.x;
  const int z  = blockIdx.z;
  const int m0 = blockIdx.x * 128, n0 = blockIdx.y * 128;
  const ushort* Bh  = p.Bh[z];
  const float* bias = p.bias[z];

  const int lane = t & 63, wave = t >> 6;
  const int wm = (wave & 1) * 64, wn = (wave >> 1) * 64;

  f32x4 acc[4][4];
#pragma unroll
  for (int i = 0; i < 4; ++i)
#pragma unroll
    for (int j = 0; j < 4; ++j) acc[i][j] = (f32x4){0.f, 0.f, 0.f, 0.f};

  // staging: rows {am, am+64}, logical chunk ac (8 elems)
  const int am = t >> 2;
  const int ac = t & 3;
  const ushort* gA  = A  + (size_t)(m0 + am) * 1024 + ac * 8;
  const ushort* gBh = Bh + (size_t)(n0 + am) * 1024 + ac * 8;
  const int sw = ((ac + (am >> 1)) & 3) * 8;  // physical elem offset (both rows)
  const int l0 = am * 32 + sw, l1 = (am + 64) * 32 + sw;

  const int fr  = lane & 15;
  const int fkb = (((lane >> 4) + (fr >> 1)) & 3) * 16;  // byte offset

  // preload tile k0=0
  f16x8 rA0, rA1, rH0, rH1;
  rA0 = *(const f16x8*)(gA);
  rA1 = *(const f16x8*)(gA + 64 * 1024);
  rH0 = *(const f16x8*)(gBh);
  rH1 = *(const f16x8*)(gBh + 64 * 1024);

  for (int k0 = 0; k0 < 1024; k0 += 32) {
    __syncthreads();  // prev compute done reading LDS
    *(f16x8*)&As[l0] = rA0;
    *(f16x8*)&As[l1] = rA1;
    *(f16x8*)&Bs[l0] = rH0;
    *(f16x8*)&Bs[l1] = rH1;
    __syncthreads();

    // prefetch next tile (overlaps the whole compute phase)
    if (k0 + 32 < 1024) {
      const int kn = k0 + 32;
      rA0 = *(const f16x8*)(gA + kn);
      rA1 = *(const f16x8*)(gA + kn + 64 * 1024);
      rH0 = *(const f16x8*)(gBh + kn);
      rH1 = *(const f16x8*)(gBh + kn + 64 * 1024);
    }

    f16x8 a[4], b_h[4];
#pragma unroll
    for (int i = 0; i < 4; ++i) {
      const int ra = (wm + i * 16 + fr) * 64 + fkb;  // bytes
      const int rb = (wn + i * 16 + fr) * 64 + fkb;
      a[i]   = *(const f16x8*)((const char*)As + ra);
      b_h[i] = *(const f16x8*)((const char*)Bs + rb);
    }
#pragma unroll
    for (int i = 0; i < 4; ++i)
#pragma unroll
      for (int j = 0; j < 4; ++j)
        acc[i][j] = __builtin_amdgcn_mfma_f32_16x16x32_f16(a[i], b_h[j], acc[i][j], 0, 0, 0);
  }

  const float osc = (QKV && z == 0) ? ECs : 1.0f;  // fold softmax scale into Q
  const int cr = (lane >> 4) * 4;
  const int cc = lane & 15;
#pragma unroll
  for (int j = 0; j < 4; ++j) {
    const int n    = n0 + wn + j * 16 + cc;
    const float bv = bias[n];
#pragma unroll
    for (int i = 0; i < 4; ++i) {
      const int mb = m0 + wm + i * 16 + cr;
#pragma unroll
      for (int r = 0; r < 4; ++r) {
        const int m   = mb + r;
        const float v = (acc[i][j][r] + bv) * osc;
        if (QKV) {
          const int b = m >> 11, s = m & 2047, h = n >> 6, hd = n & 63;
          ((ushort*)p.Out[z])[(((size_t)(b * Hc + h) * Sc + s) << 6) + hd] = f2h(v);
        } else {
          ((float*)p.Out[z])[(size_t)m * 1024 + n] = v;
        }
      }
    }
  }
}

// ---------------------------------------------------------------------------
// MFMA flash attention (single-pass, 32 kt — split-KV reverted: it added
// partial-write traffic with no occupancy gain).
// NEW: GEMM-style XOR-swizzled LDS for Ks/Vt. Rows are 64 elems (two 32-elem
// halves of 4 chunks x 8); logical chunk q of half c of row r lives at
// physical slot (q + (r>>1)) & 3. This is the exact layout the GEMM kernel
// uses, which measures 0 LDS bank conflicts vs 5.24M/dispatch for the old
// 72-stride layout (~15% of attn time). V k-relabeling (lb) is logical and
// unchanged; only physical chunk placement differs -> bit-identical results.
// QK^T zero-init hoisted (C=0 operand); s_setprio(1) around MFMA clusters
// (T5: helps attn's independently-phased blocks).
// ---------------------------------------------------------------------------
__global__ __launch_bounds__(256) void attn_mfma3(
    const ushort* __restrict__ Q, const ushort* __restrict__ K,
    const ushort* __restrict__ V, ushort* __restrict__ CTX) {
  __shared__ __align__(16) ushort Ks[64 * 64];
  __shared__ __align__(16) ushort Vt[64 * 64];  // [d][l(k) swizzled]

  const int t    = threadIdx.x;
  const int lane = t & 63, wave = t >> 6;
  const int c16 = lane & 15, quad = lane >> 4;
  const int bh = blockIdx.x, qt = blockIdx.y;
  const int bb = bh >> 4, hh = bh & 15;

  const ushort* Qb = Q + (size_t)bh * Sc * HDc + (size_t)qt * 128 * HDc;
  const ushort* Kb = K + (size_t)bh * Sc * HDc;
  const ushort* Vb = V + (size_t)bh * Sc * HDc;

  f16x8 aq[2][2];
#pragma unroll
  for (int mt = 0; mt < 2; ++mt)
#pragma unroll
    for (int c = 0; c < 2; ++c)
      aq[mt][c] = *(const f16x8*)(Qb + (size_t)(wave * 32 + mt * 16 + c16) * 64 + c * 32 + quad * 8);

  US8 ones_u;
#pragma unroll
  for (int e = 0; e < 8; ++e) ones_u.u[e] = 0x3C00;  // fp16 1.0
  const f16x8 ones = ones_u.v;
  const f32x4 kZ = (f32x4){0.f, 0.f, 0.f, 0.f};  // hoisted MFMA C=0

  f32x4 ctx[2][4], lacc[2];
#pragma unroll
  for (int mt = 0; mt < 2; ++mt) {
    lacc[mt] = (f32x4){0.f, 0.f, 0.f, 0.f};
#pragma unroll
    for (int j = 0; j < 4; ++j) ctx[mt][j] = (f32x4){0.f, 0.f, 0.f, 0.f};
  }

  // fragment reads: row = j*16+c16 -> (row>>1)&3 = (c16>>1)&3 (j*8 ≡ 0 mod 4)
  const int fslot = ((quad + (c16 >> 1)) & 3) * 8;  // physical elem offset

  // K staging: row krow, logical chunk kac of both halves
  const int krow = t >> 2, kac = t & 3;
  const int kl = krow * 64 + ((kac + (krow >> 1)) & 3) * 8;

  // V staging: thread covers logical k = kg*4..+3, d = dg*4..+3
  const int kg = t & 15, dg = t >> 4;
  const int vc   = (kg >> 3) * 32;        // half (elem offset)
  const int vq   = kg & 3;                // logical chunk within half
  const int vsub = ((kg >> 2) & 1) * 4;   // within-chunk offset

  const ushort* gK = Kb + (size_t)krow * 64 + kac * 8;
  const ushort* gV = Vb + (size_t)(kg * 4) * 64 + dg * 4;

  f16x8 kr0, kr1;
  ushort4 vr[4];
  kr0 = *(const f16x8*)(gK);
  kr1 = *(const f16x8*)(gK + 32);
#pragma unroll
  for (int i = 0; i < 4; ++i) vr[i] = *(const ushort4*)(gV + (size_t)i * 64);

  for (int kt = 0; kt < 32; ++kt) {
    __syncthreads();
    *(f16x8*)&Ks[kl]      = kr0;
    *(f16x8*)&Ks[kl + 32] = kr1;
    {
      const uint* w0 = (const uint*)&vr[0];
      const uint* w1 = (const uint*)&vr[1];
      const uint* w2 = (const uint*)&vr[2];
      const uint* w3 = (const uint*)&vr[3];
#pragma unroll
      for (int j = 0; j < 4; ++j) {
        const int  wd  = j >> 1;
        const uint sel = (j & 1) ? 0x07060302u : 0x05040100u;
        const uint lo  = __builtin_amdgcn_perm(w1[wd], w0[wd], sel);
        const uint hi  = __builtin_amdgcn_perm(w3[wd], w2[wd], sel);
        const int row  = dg * 4 + j;
        const int slot = (vq + (row >> 1)) & 3;
        *(uint2*)&Vt[row * 64 + vc + slot * 8 + vsub] = make_uint2(lo, hi);
      }
    }
    __syncthreads();

    if (kt < 31) {
      const size_t adv = (size_t)(kt + 1) * 64 * 64;
      kr0 = *(const f16x8*)(gK + adv);
      kr1 = *(const f16x8*)(gK + adv + 32);
#pragma unroll
      for (int i = 0; i < 4; ++i) vr[i] = *(const ushort4*)(gV + adv + (size_t)i * 64);
    }

    // QK^T: c=0 uses the hoisted zero C operand (no per-kt acc zeroing)
    f32x4 st[2][4];
    __builtin_amdgcn_s_setprio(1);
#pragma unroll
    for (int j = 0; j < 4; ++j) {
      const f16x8 ak0 = *(const f16x8*)&Ks[(j * 16 + c16) * 64 + fslot];
      st[0][j] = __builtin_amdgcn_mfma_f32_16x16x32_f16(ak0, aq[0][0], kZ, 0, 0, 0);
      st[1][j] = __builtin_amdgcn_mfma_f32_16x16x32_f16(ak0, aq[1][0], kZ, 0, 0, 0);
    }
#pragma unroll
    for (int j = 0; j < 4; ++j) {
      const f16x8 ak1 = *(const f16x8*)&Ks[(j * 16 + c16) * 64 + 32 + fslot];
      st[0][j] = __builtin_amdgcn_mfma_f32_16x16x32_f16(ak1, aq[0][1], st[0][j], 0, 0, 0);
      st[1][j] = __builtin_amdgcn_mfma_f32_16x16x32_f16(ak1, aq[1][1], st[1][j], 0, 0, 0);
    }
    __builtin_amdgcn_s_setprio(0);

    US8 pf[2][2];
#pragma unroll
    for (int mt = 0; mt < 2; ++mt)
#pragma unroll
      for (int c2 = 0; c2 < 2; ++c2)
#pragma unroll
        for (int w = 0; w < 4; ++w) {
          const int jj = c2 * 2 + (w >> 1);
          const int r0 = (w & 1) * 2;
          const float pe = __builtin_amdgcn_exp2f(st[mt][jj][r0]);
          const float po = __builtin_amdgcn_exp2f(st[mt][jj][r0 + 1]);
          const auto pk = __builtin_amdgcn_cvt_pkrtz(pe, po);  // __fp16 ext_vec(2)
          pf[mt][c2].w[w] = __builtin_bit_cast(uint, pk);
        }

    __builtin_amdgcn_s_setprio(1);
#pragma unroll
    for (int c2 = 0; c2 < 2; ++c2) {
      lacc[0] = __builtin_amdgcn_mfma_f32_16x16x32_f16(pf[0][c2].v, ones, lacc[0], 0, 0, 0);
      lacc[1] = __builtin_amdgcn_mfma_f32_16x16x32_f16(pf[1][c2].v, ones, lacc[1], 0, 0, 0);
#pragma unroll
      for (int j = 0; j < 4; ++j) {
        const f16x8 bv = *(const f16x8*)&Vt[(j * 16 + c16) * 64 + c2 * 32 + fslot];
        ctx[0][j] = __builtin_amdgcn_mfma_f32_16x16x32_f16(pf[0][c2].v, bv, ctx[0][j], 0, 0, 0);
        ctx[1][j] = __builtin_amdgcn_mfma_f32_16x16x32_f16(pf[1][c2].v, bv, ctx[1][j], 0, 0, 0);
      }
    }
    __builtin_amdgcn_s_setprio(0);
  }

#pragma unroll
  for (int mt = 0; mt < 2; ++mt) {
#pragma unroll
    for (int r = 0; r < 4; ++r) {
      const float inv = 1.f / lacc[mt][r];
      const int srow  = qt * 128 + wave * 32 + mt * 16 + quad * 4 + r;
      const size_t rb = ((size_t)(bb * Sc + srow)) * 1024 + hh * 64;
#pragma unroll
      for (int j = 0; j < 4; ++j)
        CTX[rb + j * 16 + c16] = f2h(ctx[mt][j][r] * inv);
    }
  }
}

extern "C" void kernel_launch(void* const* d_in, const int* in_sizes, int n_in,
                              void* d_out, int out_size, void* d_ws, size_t ws_size,
                              hipStream_t stream) {
  (void)in_sizes; (void)n_in; (void)out_size; (void)ws_size;
  const float* x  = (const float*)d_in[0];
  const float* Wq = (const float*)d_in[1];
  const float* bq = (const float*)d_in[2];
  const float* Wk = (const float*)d_in[3];
  const float* bk = (const float*)d_in[4];
  const float* Wv = (const float*)d_in[5];
  const float* bv = (const float*)d_in[6];
  const float* Wo = (const float*)d_in[7];
  const float* bo = (const float*)d_in[8];

  const size_t MB = 1024 * 1024;
  char* w    = (char*)d_ws;
  ushort* Qw  = (ushort*)(w + 0 * MB);   // [B,H,S,HD] fp16 (pre-scaled by EC)
  ushort* Kw  = (ushort*)(w + 8 * MB);
  ushort* Vw  = (ushort*)(w + 16 * MB);
  ushort* Cw  = (ushort*)(w + 24 * MB);  // ctx [M,1024] fp16
  ushort* Xh  = (ushort*)(w + 32 * MB);  // x fp16 [M,1024]
  ushort* WT  = (ushort*)(w + 40 * MB);  // 4 x 2 MB fp16 W^T planes
  ushort* Whq = WT + 0 * 1048576;
  ushort* Whk = WT + 1 * 1048576;
  ushort* Whv = WT + 2 * 1048576;
  ushort* Who = WT + 3 * 1048576;

  const dim3 blk(256);

  split_x_kernel<<<4096, blk, 0, stream>>>(x, Xh);

  SplitP sp;
  sp.W[0] = Wq; sp.W[1] = Wk; sp.W[2] = Wv; sp.W[3] = Wo;
  sp.Th[0] = Whq; sp.Th[1] = Whk; sp.Th[2] = Whv; sp.Th[3] = Who;
  split_wt_kernel<<<dim3(16, 16, 4), blk, 0, stream>>>(sp);

  GemmP pq;
  pq.Bh[0] = Whq; pq.Bh[1] = Whk; pq.Bh[2] = Whv;
  pq.bias[0] = bq; pq.bias[1] = bk; pq.bias[2] = bv;
  pq.Out[0] = Qw; pq.Out[1] = Kw; pq.Out[2] = Vw;
  gemm_f16<true><<<dim3(Mc / 128, Dc / 128, 3), blk, 0, stream>>>(Xh, pq);

  attn_mfma3<<<dim3(2 * Hc, Sc / 128), blk, 0, stream>>>(Qw, Kw, Vw, Cw);

  GemmP po;
  po.Bh[0] = po.Bh[1] = po.Bh[2] = Who;
  po.bias[0] = po.bias[1] = po.bias[2] = bo;
  po.Out[0] = po.Out[1] = po.Out[2] = d_out;
  gemm_f16<false><<<dim3(Mc / 128, Dc / 128, 1), blk, 0, stream>>>(Cw, po);
}